// Round 1
// 429.705 us; speedup vs baseline: 1.0171x; 1.0171x over previous
//
#include <hip/hip_runtime.h>

// Problem: Sampler — pooled = mean over stride-2 grid of b, then 2 tiny FCs.
// Input a / attn_w / attn_b are dead (attn is DCE'd in the reference).
// b: [8,128,256,256] f32. Output: [8,128,1,1] f32 (1024 elems).
//
// R1 change: d_ws is NOT touched at all. The 1024-float pooled intermediate
// is staged in d_out itself (same size), so the harness's 1-GiB workspace
// re-poison fills (2 x ~163 us, the top dispatches in rocprof) have nothing
// to poison on our behalf. FC is batch-parallel (8 blocks) with float4
// weight staging. Reduction order is bit-identical to the passing kernel.

#define B_DIM 8
#define C_DIM 128
#define H_DIM 256
#define W_DIM 256
#define HWSZ  (H_DIM * W_DIM)      // 65536
#define NPLANE (B_DIM * C_DIM)     // 1024

// Kernel 1: per-plane reduction over even rows / even cols.
// One block per (b,c) plane. Each wave reads one full even row per iter
// as 64 coalesced float4 (1 KB), sums .x and .z (the even columns).
// Writes pooled[plane] into d_out[plane] (all 1024 elems written).
__global__ __launch_bounds__(256) void pool_kernel(const float* __restrict__ b,
                                                   float* __restrict__ pooled) {
    const int plane = blockIdx.x;                 // 0..1023
    const float* base = b + (size_t)plane * HWSZ;
    const int tid  = threadIdx.x;
    const int col4 = tid & 63;                    // float4 index within row (0..63)
    const int rq   = tid >> 6;                    // wave id 0..3

    float acc = 0.f;
    #pragma unroll
    for (int i = 0; i < 32; ++i) {
        const int er  = rq + 4 * i;               // even-row index 0..127
        const int row = er << 1;                  // actual row (even)
        float4 v = ((const float4*)(base + (size_t)row * W_DIM))[col4];
        acc += v.x + v.z;                         // even columns only
    }

    // wave (64-lane) tree reduce
    #pragma unroll
    for (int off = 32; off > 0; off >>= 1)
        acc += __shfl_down(acc, off, 64);

    __shared__ float ws[4];
    if ((tid & 63) == 0) ws[rq] = acc;
    __syncthreads();
    if (tid == 0)
        pooled[plane] = (ws[0] + ws[1] + ws[2] + ws[3]) * (1.0f / 65536.0f);
}

// Kernel 2: hidden = relu(pooled @ fc1^T) ; out = hidden @ fc2^T.
// One block per batch (8 blocks x 256 threads). Block bb reads ONLY
// out[bb*128 .. bb*128+127] (its pooled row, written by kernel 1), stages
// it in LDS behind a __syncthreads, then overwrites the same range.
// No other block touches that range -> no hazard. LDS rows padded (+1)
// to dodge same-bank serialization.
__global__ __launch_bounds__(256) void fc_kernel(const float* __restrict__ fc1_w,  // [32,128]
                                                 const float* __restrict__ fc2_w,  // [128,32]
                                                 float* out) {                     // [8,128], holds pooled on entry
    __shared__ float sp[C_DIM];                   // pooled row for this batch
    __shared__ float s_fc1[32 * 129];             // padded rows
    __shared__ float s_fc2[128 * 33];             // padded rows
    __shared__ float sh[32];                      // hidden

    const int bb  = blockIdx.x;                   // batch 0..7
    const int tid = threadIdx.x;

    // stage pooled row (128 floats = 32 float4)
    if (tid < 32) {
        float4 v = ((const float4*)(out + bb * C_DIM))[tid];
        float* d = sp + tid * 4;
        d[0] = v.x; d[1] = v.y; d[2] = v.z; d[3] = v.w;
    }
    // stage fc1: 4096 floats = 1024 float4, row len 128 -> 32 float4/row
    for (int i4 = tid; i4 < 1024; i4 += 256) {
        float4 v = ((const float4*)fc1_w)[i4];
        const int j = i4 >> 5, c4 = (i4 & 31) * 4;
        float* d = s_fc1 + j * 129 + c4;
        d[0] = v.x; d[1] = v.y; d[2] = v.z; d[3] = v.w;
    }
    // stage fc2: 4096 floats = 1024 float4, row len 32 -> 8 float4/row
    for (int i4 = tid; i4 < 1024; i4 += 256) {
        float4 v = ((const float4*)fc2_w)[i4];
        const int o = i4 >> 3, j4 = (i4 & 7) * 4;
        float* d = s_fc2 + o * 33 + j4;
        d[0] = v.x; d[1] = v.y; d[2] = v.z; d[3] = v.w;
    }
    __syncthreads();

    // hidden[j], j=0..31 (order of FMAs identical to previous passing kernel)
    if (tid < 32) {
        const float* w = s_fc1 + tid * 129;
        float h = 0.f;
        #pragma unroll
        for (int c = 0; c < C_DIM; ++c) h += sp[c] * w[c];
        sh[tid] = h > 0.f ? h : 0.f;
    }
    __syncthreads();

    // out[bb][o], o=0..127
    if (tid < 128) {
        const float* w = s_fc2 + tid * 33;
        float a = 0.f;
        #pragma unroll
        for (int j = 0; j < 32; ++j) a += sh[j] * w[j];
        out[bb * C_DIM + tid] = a;
    }
}

extern "C" void kernel_launch(void* const* d_in, const int* in_sizes, int n_in,
                              void* d_out, int out_size, void* d_ws, size_t ws_size,
                              hipStream_t stream) {
    const float* b     = (const float*)d_in[1];
    const float* fc1_w = (const float*)d_in[4];
    const float* fc2_w = (const float*)d_in[5];
    float* out = (float*)d_out;
    (void)d_ws; (void)ws_size;                    // workspace intentionally untouched

    pool_kernel<<<NPLANE, 256, 0, stream>>>(b, out);   // d_out holds pooled
    fc_kernel<<<B_DIM, 256, 0, stream>>>(fc1_w, fc2_w, out);
}